// Round 17
// baseline (51.548 us; speedup 1.0000x reference)
//
#include <hip/hip_runtime.h>
#include <hip/hip_bf16.h>

// MyDeConv1D as GEMM: out[b,t,f] = sum_{j,c} x[b,t+28-4j,c]*W[c,j,f] + cnt(t)*256*bias[f]
// M=32768, N=256, K=2048, bf16 MFMA 16x16x32.
// R17 = R16 machinery at 4 blocks/CU (4 independent barrier domains/SIMD ->
//   MFMA/LDS/VMEM pipes overlap via TLP instead of serializing).
//   Block 64r x 128f, 4 waves (each 64r x 32f, MF=4 NF=2, acc 32 VGPR).
//   Grid 1024 = 32t x 16b x 2fh. LDS 23.5 KB. Pinned-asm B ring (2 loads/
//   issue), counted per-lane vmcnt ledger, gload_lds A-staging + CVT pass.

#define B_   16
#define T_   2048
#define C_   256
#define KT   8
#define F_   256
#define SH   28
#define BT   64
#define WIN  92                  // rows per tile
#define FB   11776               // f32 staging buf bytes (92*8 granules * 16B)
#define ABF  11776               // bf16 tiles base offset
#define ABFB 5888                // bytes per bf16 tile (92*4 granules * 16B)
// total LDS = FB + 2*ABFB = 23552 B

typedef __attribute__((ext_vector_type(8))) short short8;
typedef __attribute__((ext_vector_type(4))) float floatx4;
typedef __attribute__((ext_vector_type(4))) int   intx4;

__device__ inline void gload16(const void* g, void* l) {
    __builtin_amdgcn_global_load_lds(
        (const __attribute__((address_space(1))) void*)g,
        (__attribute__((address_space(3))) void*)l, 16, 0, 0);
}

__device__ inline short8 cvt8(float4 a, float4 b) {
    float v[8] = {a.x, a.y, a.z, a.w, b.x, b.y, b.z, b.w};
    short8 r;
    #pragma unroll
    for (int i = 0; i < 8; ++i) {
        __hip_bfloat16 h = __float2bfloat16(v[i]);
        r[i] = *reinterpret_cast<const short*>(&h);
    }
    return r;
}

// Wf frag order: fid = S*16 + g, S = c*8 + j. frag (S,g): lane(l16,q) holds
// B[k=q*8+i][f=g*16+l16], c = c*32 + q*8 + i. 1KB/frag coalesced.
__global__ __launch_bounds__(256) void wprep_kernel(const float* __restrict__ W,
                                                    ushort* __restrict__ Wf) {
    const int tid  = threadIdx.x;
    const int fid  = blockIdx.x * 4 + (tid >> 6);   // 0..1023
    const int lane = tid & 63;
    const int g    = fid & 15;
    const int S    = fid >> 4;
    const int j    = S & 7, c = S >> 3;
    const int c0   = c * 32 + (lane >> 4) * 8;
    const int f    = g * 16 + (lane & 15);
    short8 pk;
    #pragma unroll
    for (int i = 0; i < 8; ++i) {
        __hip_bfloat16 h = __float2bfloat16(W[((c0 + i) * KT + j) * F_ + f]);
        pk[i] = *reinterpret_cast<const short*>(&h);
    }
    *reinterpret_cast<short8*>(Wf + (size_t)fid * 512 + lane * 8) = pk;
}

__global__ __launch_bounds__(256, 4) void deconv_kernel(
        const float* __restrict__ x, const ushort* __restrict__ Wf,
        const float* __restrict__ bias, float* __restrict__ out) {
    __shared__ alignas(16) char smem[23552];
    const int bid = blockIdx.x;                 // (tt*16 + b)*2 + fh
    const int fh  = bid & 1;
    const int tb  = bid >> 1;
    const int b   = tb & 15;
    const int t0  = (tb >> 4) * BT;
    const int tid = threadIdx.x;
    const int wf  = tid >> 6, lane = tid & 63;  // wave owns f [wf*32, wf*32+32)
    const int l16 = lane & 15, q = lane >> 4;
    const char* wfbase = (const char*)Wf +
        (size_t)(fh * 8 + wf * 2) * 1024 + (size_t)lane * 16;

#define VMW(N_) do { asm volatile("s_waitcnt vmcnt(" #N_ ")" ::: "memory"); \
        __builtin_amdgcn_sched_barrier(0); } while (0)
#define LKW() do { asm volatile("s_waitcnt lgkmcnt(0)" ::: "memory");       \
        __builtin_amdgcn_sched_barrier(0); } while (0)
#define BAR() do { __builtin_amdgcn_sched_barrier(0);                       \
        __builtin_amdgcn_s_barrier();                                       \
        asm volatile("" ::: "memory");                                      \
        __builtin_amdgcn_sched_barrier(0); } while (0)

    // A stage round k (k=0..2) for chunk cc -> f32 buf. Linear dest granule u;
    // source granule v = (s - row) mod 8 so CVT reads are bank-uniform.
#define A_ROUND(k_, cc_) do {                                               \
        const int u_ = (k_) * 256 + tid;                                    \
        if ((k_) < 2 || tid < 224) {                                        \
            const int row_ = u_ >> 3, s_ = u_ & 7;                          \
            const int v_   = (s_ + 8 - (row_ & 7)) & 7;                     \
            int tr_ = t0 + row_; if (tr_ > T_ - 1) tr_ = T_ - 1;            \
            gload16(x + ((size_t)(b * T_ + tr_) * C_ + (cc_) * 32 + v_ * 4),\
                    smem + ((k_) * 256 + wf * 64) * 16);                    \
        } } while (0)

    // pinned B frag loads (flat 64b vaddr), tile S -> ring slot sl (NF=2)
#define B_ISSUE(S_, sl_) do {                                               \
        const char* p_ = wfbase + (size_t)(S_) * 16384;                     \
        asm volatile("global_load_dwordx4 %0, %1, off"                      \
            : "=v"(bR[sl_][0]) : "v"(p_) : "memory");                       \
        asm volatile("global_load_dwordx4 %0, %1, off offset:1024"          \
            : "=v"(bR[sl_][1]) : "v"(p_) : "memory");                       \
        } while (0)

    // f32 -> bf16 convert round r (r=0..1), dest tile parity par
#define CVT_ROUND(r_, par_) do {                                            \
        if ((r_) < 1 || tid < 112) {                                        \
            const int task_ = (r_) * 256 + tid;                             \
            const int row_ = task_ >> 2, g_ = task_ & 3;                    \
            const int s1_ = (2 * g_ + row_) & 7;                            \
            const int s2_ = (2 * g_ + 1 + row_) & 7;                        \
            float4 u0_ = *(const float4*)(smem + (row_ * 8 + s1_) * 16);    \
            float4 u1_ = *(const float4*)(smem + (row_ * 8 + s2_) * 16);    \
            short8 pk_ = {0,0,0,0,0,0,0,0};                                 \
            if (t0 + row_ < T_) pk_ = cvt8(u0_, u1_);                       \
            const int p_ = g_ ^ ((row_ >> 1) & 3);                          \
            *(short8*)(smem + ABF + (par_) * ABFB + (row_ * 4 + p_) * 16)   \
                = pk_;                                                      \
        } } while (0)

    // A frags for tap j from tile buf_ (C-level: compiler pipelines via lgkmcnt)
#define LOAD_A(buf_, j_, arr) do {                                          \
        const char* ab_ = smem + ABF + (buf_) * ABFB;                       \
        _Pragma("unroll")                                                   \
        for (int mf = 0; mf < 4; ++mf) {                                    \
            const int row_ = (SH - 4 * (j_)) + mf * 16 + l16;               \
            const int p_   = q ^ ((row_ >> 1) & 3);                         \
            arr[mf] = *(const short8*)(ab_ + (row_ * 4 + p_) * 16);         \
        } } while (0)

#define MFMA_TAP(arr, slot_) do {                                           \
        __builtin_amdgcn_s_setprio(1);                                      \
        _Pragma("unroll")                                                   \
        for (int mf = 0; mf < 4; ++mf)                                      \
            _Pragma("unroll")                                               \
            for (int nf = 0; nf < 2; ++nf)                                  \
                acc[mf][nf] = __builtin_amdgcn_mfma_f32_16x16x32_bf16(      \
                    arr[mf], *(short8*)&bR[slot_][nf],                      \
                    acc[mf][nf], 0, 0, 0);                                  \
        __builtin_amdgcn_s_setprio(0);                                      \
        } while (0)

#define CHUNK(c_) do {                                                      \
        LOAD_A((c_) & 1, 0, a0);                                            \
        A_ROUND(0, (c_)+1); A_ROUND(1, (c_)+1); A_ROUND(2, (c_)+1);         \
        LOAD_A((c_) & 1, 1, a1);                                            \
        B_ISSUE((c_)*8+2, (((c_)*8+2)%3)); VMW(7);                          \
        MFMA_TAP(a0, (((c_)*8+0)%3));                                       \
        LOAD_A((c_) & 1, 2, a0);                                            \
        B_ISSUE((c_)*8+3, (((c_)*8+3)%3)); VMW(7);                          \
        MFMA_TAP(a1, (((c_)*8+1)%3));                                       \
        LOAD_A((c_) & 1, 3, a1);                                            \
        B_ISSUE((c_)*8+4, (((c_)*8+4)%3)); VMW(4);                          \
        BAR();                                                              \
        MFMA_TAP(a0, (((c_)*8+2)%3));                                       \
        LOAD_A((c_) & 1, 4, a0);                                            \
        B_ISSUE((c_)*8+5, (((c_)*8+5)%3)); VMW(4);                          \
        MFMA_TAP(a1, (((c_)*8+3)%3));                                       \
        LOAD_A((c_) & 1, 5, a1);                                            \
        CVT_ROUND(0, ((c_)+1)&1);                                           \
        B_ISSUE((c_)*8+6, (((c_)*8+6)%3)); VMW(4);                          \
        MFMA_TAP(a0, (((c_)*8+4)%3));                                       \
        LOAD_A((c_) & 1, 6, a0);                                            \
        CVT_ROUND(1, ((c_)+1)&1);                                           \
        B_ISSUE((c_)*8+7, (((c_)*8+7)%3)); VMW(4);                          \
        MFMA_TAP(a1, (((c_)*8+5)%3));                                       \
        LOAD_A((c_) & 1, 7, a1);                                            \
        B_ISSUE((c_)*8+8, (((c_)*8+8)%3)); VMW(4);                          \
        MFMA_TAP(a0, (((c_)*8+6)%3));                                       \
        B_ISSUE((c_)*8+9, (((c_)*8+9)%3)); VMW(4);                          \
        MFMA_TAP(a1, (((c_)*8+7)%3));                                       \
        LKW(); BAR();                                                       \
        } while (0)

    float bf2[2];
    bf2[0] = bias[fh * 128 + wf * 32 + l16];
    bf2[1] = bias[fh * 128 + wf * 32 + 16 + l16];

    floatx4 acc[4][2];
    #pragma unroll
    for (int mf = 0; mf < 4; ++mf) {
        acc[mf][0] = (floatx4){0.f, 0.f, 0.f, 0.f};
        acc[mf][1] = (floatx4){0.f, 0.f, 0.f, 0.f};
    }

    short8 a0[4], a1[4];          // depth-2 A ring (32 VGPR)
    intx4  bR[3][2];              // pinned B ring (24 VGPR)

    // ---- prologue: stage chunk 0, prime B(0),B(1), convert tile 0 ----
    A_ROUND(0, 0); A_ROUND(1, 0); A_ROUND(2, 0);
    B_ISSUE(0, 0); B_ISSUE(1, 1);
    VMW(4);                        // retire the 3 A gloads; B(0),B(1) in flight
    BAR();
    CVT_ROUND(0, 0); CVT_ROUND(1, 0);
    LKW(); BAR();

    CHUNK(0); CHUNK(1); CHUNK(2); CHUNK(3);
    CHUNK(4); CHUNK(5); CHUNK(6);

    // ---- last chunk (c=7): no staging, no CVT ----
    LOAD_A(1, 0, a0);
    LOAD_A(1, 1, a1);
    B_ISSUE(58, 1); VMW(4); MFMA_TAP(a0, 2); LOAD_A(1, 2, a0);
    B_ISSUE(59, 2); VMW(4); MFMA_TAP(a1, 0); LOAD_A(1, 3, a1);
    B_ISSUE(60, 0); VMW(4); MFMA_TAP(a0, 1); LOAD_A(1, 4, a0);
    B_ISSUE(61, 1); VMW(4); MFMA_TAP(a1, 2); LOAD_A(1, 5, a1);
    B_ISSUE(62, 2); VMW(4); MFMA_TAP(a0, 0); LOAD_A(1, 6, a0);
    B_ISSUE(63, 0); VMW(4); MFMA_TAP(a1, 1); LOAD_A(1, 7, a1);
    VMW(2); MFMA_TAP(a0, 2);
    VMW(0); MFMA_TAP(a1, 0);

    // ---- epilogue: + cnt(t)*256*bias; C/D map col=l16 (f), row=q*4+r ----
    #pragma unroll
    for (int mf = 0; mf < 4; ++mf) {
        #pragma unroll
        for (int nf = 0; nf < 2; ++nf) {
            const int f = fh * 128 + wf * 32 + nf * 16 + l16;
            #pragma unroll
            for (int r = 0; r < 4; ++r) {
                const int t = t0 + mf * 16 + q * 4 + r;
                const int jmin = (t < T_ - SH) ? 0 : (((t - (T_ - SH)) >> 2) + 1);
                out[(size_t)(b * T_ + t) * F_ + f] =
                    acc[mf][nf][r] + (float)(8 - jmin) * 256.0f * bf2[nf];
            }
        }
    }
#undef VMW
#undef LKW
#undef BAR
#undef A_ROUND
#undef B_ISSUE
#undef CVT_ROUND
#undef LOAD_A
#undef MFMA_TAP
#undef CHUNK
}

extern "C" void kernel_launch(void* const* d_in, const int* in_sizes, int n_in,
                              void* d_out, int out_size, void* d_ws, size_t ws_size,
                              hipStream_t stream) {
    const float* x    = (const float*)d_in[0];
    const float* W    = (const float*)d_in[1];   // (C,KT,F)
    const float* bias = (const float*)d_in[2];
    float* out = (float*)d_out;
    ushort* Wf = (ushort*)d_ws;                  // 1 MiB scratch

    wprep_kernel<<<256, 256, 0, stream>>>(W, Wf);
    deconv_kernel<<<1024, 256, 0, stream>>>(x, Wf, bias, out);
}

// Round 18
// 47.766 us; speedup vs baseline: 1.0792x; 1.0792x over previous
//
#include <hip/hip_runtime.h>
#include <hip/hip_bf16.h>

// MyDeConv1D as GEMM: out[b,t,f] = sum_{j,c} x[b,t+28-4j,c]*W[c,j,f] + cnt(t)*256*bias[f]
// M=32768, N=256, K=2048.
// R18: 32x32x16 MFMA (R6-verified layout, -17% MFMA pipe, -50% MFMA instrs),
//   reg-staged bf16 path (pinned asm f32 loads -> in-reg cvt -> swizzled
//   ds_write; no f32 LDS, no CVT pass), stage-2-ahead SL, exec-uniform VMEM
//   issue + exact per-wave vmcnt ledger, 1 barrier/chunk. Block 128r x 128f,
//   4 waves (2wm x 2fq, wave = 64r x 64f as 2x2 of 32x32), 512 blocks = 2/CU.
//   LDS 19.5 KB (2 bf16 tiles).

#define B_   16
#define T_   2048
#define C_   256
#define KT   8
#define F_   256
#define SH   28
#define BT   128
#define ABFB 9984               // bytes per bf16 tile (156 rows x 64B)

typedef __attribute__((ext_vector_type(8))) short short8;
typedef __attribute__((ext_vector_type(4))) float floatx4;
typedef __attribute__((ext_vector_type(16))) float floatx16;
typedef __attribute__((ext_vector_type(4))) int   intx4;

// Wf: fid = (S*4 + fqg)*4 + kh*2 + nf, S = chunk*8 + j, fqg = global f-quarter.
// frag: lane(l5,h) holds B[k=kh*16+h*8+i][f=fqg*64+nf*32+l5], c = chunk*32+k.
// 1KB/frag coalesced. (32x32x16 layout verified in R6.)
__global__ __launch_bounds__(256) void wprep_kernel(const float* __restrict__ W,
                                                    ushort* __restrict__ Wf) {
    const int tid  = threadIdx.x;
    const int fid  = blockIdx.x * 4 + (tid >> 6);   // 0..1023
    const int lane = tid & 63;
    const int l5 = lane & 31, h = lane >> 5;
    const int knf = fid & 3, kh = knf >> 1, nf = knf & 1;
    const int fqg = (fid >> 2) & 3;
    const int S   = fid >> 4;
    const int j   = S & 7, ch = S >> 3;
    const int c0  = ch * 32 + kh * 16 + h * 8;
    const int f   = fqg * 64 + nf * 32 + l5;
    short8 pk;
    #pragma unroll
    for (int i = 0; i < 8; ++i) {
        __hip_bfloat16 v = __float2bfloat16(W[((c0 + i) * KT + j) * F_ + f]);
        pk[i] = *reinterpret_cast<const short*>(&v);
    }
    *reinterpret_cast<short8*>(Wf + (size_t)fid * 512 + lane * 8) = pk;
}

__device__ inline short8 cvt8v(floatx4 a, floatx4 b) {
    short8 r;
    #pragma unroll
    for (int i = 0; i < 4; ++i) {
        __hip_bfloat16 h = __float2bfloat16(a[i]);
        r[i] = *reinterpret_cast<const short*>(&h);
    }
    #pragma unroll
    for (int i = 0; i < 4; ++i) {
        __hip_bfloat16 h = __float2bfloat16(b[i]);
        r[i + 4] = *reinterpret_cast<const short*>(&h);
    }
    return r;
}

__global__ __launch_bounds__(256) void deconv_kernel(
        const float* __restrict__ x, const ushort* __restrict__ Wf,
        const float* __restrict__ bias, float* __restrict__ out) {
    __shared__ alignas(16) char smem[2 * ABFB];     // 19968 B
    const int bid = blockIdx.x;                 // (tt*16 + b)*2 + fh
    const int fh  = bid & 1;
    const int tb  = bid >> 1;
    const int b   = tb & 15;
    const int t0  = (tb >> 4) * BT;
    const int tid = threadIdx.x;
    const int w   = tid >> 6, lane = tid & 63;
    const int l5  = lane & 31, h = lane >> 5;
    const int wm  = w >> 1, fq2 = w & 1;
    const char* wfbase = (const char*)Wf +
        (size_t)(fh * 2 + fq2) * 4096 + (size_t)lane * 16;
    const int srow = tid >> 2, sg = tid & 3;    // stage task base (row, granule)

#define VMW(N_) do { asm volatile("s_waitcnt vmcnt(" #N_ ")" ::: "memory"); \
        __builtin_amdgcn_sched_barrier(0); } while (0)
#define LKW() do { asm volatile("s_waitcnt lgkmcnt(0)" ::: "memory");       \
        __builtin_amdgcn_sched_barrier(0); } while (0)
#define BAR() do { __builtin_amdgcn_sched_barrier(0);                       \
        __builtin_amdgcn_s_barrier();                                       \
        asm volatile("" ::: "memory");                                      \
        __builtin_amdgcn_sched_barrier(0); } while (0)

    // pinned stage loads for chunk cc: 3 rounds x (2 x dwordx4 f32), uniform
    // across all lanes (clamped row) so the per-wave vmcnt ledger is exact.
#define SL_ISSUE(cc_) do {                                                  \
        _Pragma("unroll")                                                   \
        for (int k = 0; k < 3; ++k) {                                       \
            int row_ = srow + 64 * k;                                       \
            int tr_ = t0 + row_; if (tr_ > T_ - 1) tr_ = T_ - 1;            \
            const char* p_ = (const char*)(x +                              \
                ((size_t)(b * T_ + tr_) * C_ + (cc_) * 32 + sg * 8));       \
            asm volatile("global_load_dwordx4 %0, %1, off"                  \
                : "=v"(sl[k][0]) : "v"(p_) : "memory");                     \
            asm volatile("global_load_dwordx4 %0, %1, off offset:16"        \
                : "=v"(sl[k][1]) : "v"(p_) : "memory");                     \
        } } while (0)

    // convert + swizzled ds_write, one round (k=0..2), guarded on write side
#define WR_ROUND(k_, buf_) do {                                             \
        const int row_ = srow + 64 * (k_);                                  \
        if (row_ < 156) {                                                   \
            short8 pk_ = {0,0,0,0,0,0,0,0};                                 \
            if (t0 + row_ < T_) pk_ = cvt8v(sl[k_][0], sl[k_][1]);          \
            const int p_ = sg ^ ((row_ >> 1) & 3);                          \
            *(short8*)(smem + (buf_) * ABFB + row_ * 64 + p_ * 16) = pk_;   \
        } } while (0)

    // pinned B frag loads: 4 x dwordx4 (kh*2+nf order), tile S -> ring slot
#define B_ISSUE(S_, sl_) do {                                               \
        const char* p_ = wfbase + (size_t)(S_) * 16384;                     \
        asm volatile("global_load_dwordx4 %0, %1, off"                      \
            : "=v"(bR[sl_][0]) : "v"(p_) : "memory");                       \
        asm volatile("global_load_dwordx4 %0, %1, off offset:1024"          \
            : "=v"(bR[sl_][1]) : "v"(p_) : "memory");                       \
        asm volatile("global_load_dwordx4 %0, %1, off offset:2048"          \
            : "=v"(bR[sl_][2]) : "v"(p_) : "memory");                       \
        asm volatile("global_load_dwordx4 %0, %1, off offset:3072"          \
            : "=v"(bR[sl_][3]) : "v"(p_) : "memory");                       \
        } while (0)

    // A frags for tap j from tile buf_: arr[kh*2+mf], row = wm*64+SH-4j+mf*32+l5,
    // granule g = kh*2+h, phys p = g^((row>>1)&3). C-level (compiler pipelines).
#define LOAD_A(buf_, j_, arr) do {                                          \
        const char* ab_ = smem + (buf_) * ABFB;                             \
        _Pragma("unroll")                                                   \
        for (int kh = 0; kh < 2; ++kh)                                      \
            _Pragma("unroll")                                               \
            for (int mf = 0; mf < 2; ++mf) {                                \
                const int row_ = wm * 64 + (SH - 4 * (j_)) + mf * 32 + l5;  \
                const int p_ = (kh * 2 + h) ^ ((row_ >> 1) & 3);            \
                arr[kh * 2 + mf] = *(const short8*)(ab_ + row_ * 64 +       \
                                                    p_ * 16);               \
            } } while (0)

#define MFMA_TAP(arr, slot_) do {                                           \
        __builtin_amdgcn_s_setprio(1);                                      \
        _Pragma("unroll")                                                   \
        for (int mf = 0; mf < 2; ++mf)                                      \
            _Pragma("unroll")                                               \
            for (int nf = 0; nf < 2; ++nf) {                                \
                acc[mf][nf] = __builtin_amdgcn_mfma_f32_32x32x16_bf16(      \
                    arr[0 * 2 + mf], *(short8*)&bR[slot_][0 * 2 + nf],      \
                    acc[mf][nf], 0, 0, 0);                                  \
                acc[mf][nf] = __builtin_amdgcn_mfma_f32_32x32x16_bf16(      \
                    arr[1 * 2 + mf], *(short8*)&bR[slot_][1 * 2 + nf],      \
                    acc[mf][nf], 0, 0, 0);                                  \
            }                                                               \
        __builtin_amdgcn_s_setprio(0);                                      \
        } while (0)

    // steady chunk (c = 1..6): N = [14,14,8,8,8,8,8,8]; DOSL = (c <= 5)
#define CHUNK_STEADY(c_, DOSL_) do {                                        \
        const int bf_ = (c_) & 1;                                           \
        LOAD_A(bf_, 0, aA); LOAD_A(bf_, 1, aB);                             \
        B_ISSUE((c_)*8+2, (((c_)*8+2)%3)); VMW(14);                         \
        MFMA_TAP(aA, (((c_)*8+0)%3)); LOAD_A(bf_, 2, aA);                   \
        B_ISSUE((c_)*8+3, (((c_)*8+3)%3)); VMW(14);                         \
        MFMA_TAP(aB, (((c_)*8+1)%3)); LOAD_A(bf_, 3, aB);                   \
        B_ISSUE((c_)*8+4, (((c_)*8+4)%3)); VMW(8);                          \
        MFMA_TAP(aA, (((c_)*8+2)%3)); LOAD_A(bf_, 4, aA);                   \
        B_ISSUE((c_)*8+5, (((c_)*8+5)%3)); VMW(8);                          \
        MFMA_TAP(aB, (((c_)*8+3)%3)); LOAD_A(bf_, 5, aB);                   \
        WR_ROUND(0, bf_ ^ 1);                                               \
        B_ISSUE((c_)*8+6, (((c_)*8+6)%3)); VMW(8);                          \
        MFMA_TAP(aA, (((c_)*8+4)%3)); LOAD_A(bf_, 6, aA);                   \
        WR_ROUND(1, bf_ ^ 1);                                               \
        B_ISSUE((c_)*8+7, (((c_)*8+7)%3)); VMW(8);                          \
        MFMA_TAP(aB, (((c_)*8+5)%3)); LOAD_A(bf_, 7, aB);                   \
        WR_ROUND(2, bf_ ^ 1);                                               \
        B_ISSUE((c_)*8+8, (((c_)*8+8)%3)); VMW(8);                          \
        MFMA_TAP(aA, (((c_)*8+6)%3));                                       \
        B_ISSUE((c_)*8+9, (((c_)*8+9)%3)); VMW(8);                          \
        MFMA_TAP(aB, (((c_)*8+7)%3));                                       \
        if (DOSL_) SL_ISSUE((c_) + 2);                                      \
        LKW(); BAR();                                                       \
        } while (0)

    float bf2[2];
    bf2[0] = bias[fh * 128 + fq2 * 64 + l5];
    bf2[1] = bias[fh * 128 + fq2 * 64 + 32 + l5];

    floatx16 acc[2][2];
    #pragma unroll
    for (int mf = 0; mf < 2; ++mf)
        #pragma unroll
        for (int nf = 0; nf < 2; ++nf)
            #pragma unroll
            for (int r = 0; r < 16; ++r) acc[mf][nf][r] = 0.f;

    short8  aA[4], aB[4];         // A tap rings (32 VGPR)
    intx4   bR[3][4];             // pinned B ring (48 VGPR)
    floatx4 sl[3][2];             // stage regs (24 VGPR)

    // ---- prologue ----
    SL_ISSUE(0);
    VMW(0);
    WR_ROUND(0, 0); WR_ROUND(1, 0); WR_ROUND(2, 0);
    SL_ISSUE(1);
    B_ISSUE(0, 0); B_ISSUE(1, 1);
    LKW(); BAR();

    // ---- chunk 0: entry [SL1(6), B0, B1] -> all VMW(8) ----
    {
        LOAD_A(0, 0, aA); LOAD_A(0, 1, aB);
        B_ISSUE(2, 2);  VMW(8); MFMA_TAP(aA, 0); LOAD_A(0, 2, aA);
        B_ISSUE(3, 0);  VMW(8); MFMA_TAP(aB, 1); LOAD_A(0, 3, aB);
        B_ISSUE(4, 1);  VMW(8); MFMA_TAP(aA, 2); LOAD_A(0, 4, aA);
        B_ISSUE(5, 2);  VMW(8); MFMA_TAP(aB, 0); LOAD_A(0, 5, aB);
        WR_ROUND(0, 1);
        B_ISSUE(6, 0);  VMW(8); MFMA_TAP(aA, 1); LOAD_A(0, 6, aA);
        WR_ROUND(1, 1);
        B_ISSUE(7, 1);  VMW(8); MFMA_TAP(aB, 2); LOAD_A(0, 7, aB);
        WR_ROUND(2, 1);
        B_ISSUE(8, 2);  VMW(8); MFMA_TAP(aA, 0);
        B_ISSUE(9, 0);  VMW(8); MFMA_TAP(aB, 1);
        SL_ISSUE(2);
        LKW(); BAR();
    }

    CHUNK_STEADY(1, 1); CHUNK_STEADY(2, 1); CHUNK_STEADY(3, 1);
    CHUNK_STEADY(4, 1); CHUNK_STEADY(5, 1); CHUNK_STEADY(6, 0);

    // ---- chunk 7: no SL, no WR; N = [8,8,8,8,8,8,4,0] ----
    {
        LOAD_A(1, 0, aA); LOAD_A(1, 1, aB);
        B_ISSUE(58, 1); VMW(8); MFMA_TAP(aA, 2); LOAD_A(1, 2, aA);
        B_ISSUE(59, 2); VMW(8); MFMA_TAP(aB, 0); LOAD_A(1, 3, aB);
        B_ISSUE(60, 0); VMW(8); MFMA_TAP(aA, 1); LOAD_A(1, 4, aA);
        B_ISSUE(61, 1); VMW(8); MFMA_TAP(aB, 2); LOAD_A(1, 5, aB);
        B_ISSUE(62, 2); VMW(8); MFMA_TAP(aA, 0); LOAD_A(1, 6, aA);
        B_ISSUE(63, 0); VMW(8); MFMA_TAP(aB, 1); LOAD_A(1, 7, aB);
        VMW(4); MFMA_TAP(aA, 2);
        VMW(0); MFMA_TAP(aB, 0);
    }

    // ---- epilogue: + cnt(t)*256*bias ----
    // 32x32 C/D map (m74/m101, R6-verified): col = l5, row = (r&3)+8*(r>>2)+4*h
    #pragma unroll
    for (int mf = 0; mf < 2; ++mf) {
        #pragma unroll
        for (int nf = 0; nf < 2; ++nf) {
            const int f = fh * 128 + fq2 * 64 + nf * 32 + l5;
            #pragma unroll
            for (int r = 0; r < 16; ++r) {
                const int rowin = (r & 3) + 8 * (r >> 2) + 4 * h;
                const int t = t0 + wm * 64 + mf * 32 + rowin;
                const int jmin = (t < T_ - SH) ? 0 : (((t - (T_ - SH)) >> 2) + 1);
                out[(size_t)(b * T_ + t) * F_ + f] =
                    acc[mf][nf][r] + (float)(8 - jmin) * 256.0f * bf2[nf];
            }
        }
    }
#undef VMW
#undef LKW
#undef BAR
#undef SL_ISSUE
#undef WR_ROUND
#undef B_ISSUE
#undef LOAD_A
#undef MFMA_TAP
#undef CHUNK_STEADY
}

extern "C" void kernel_launch(void* const* d_in, const int* in_sizes, int n_in,
                              void* d_out, int out_size, void* d_ws, size_t ws_size,
                              hipStream_t stream) {
    const float* x    = (const float*)d_in[0];
    const float* W    = (const float*)d_in[1];   // (C,KT,F)
    const float* bias = (const float*)d_in[2];
    float* out = (float*)d_out;
    ushort* Wf = (ushort*)d_ws;                  // 1 MiB scratch

    wprep_kernel<<<256, 256, 0, stream>>>(W, Wf);
    deconv_kernel<<<512, 256, 0, stream>>>(x, Wf, bias, out);
}

// Round 20
// 44.467 us; speedup vs baseline: 1.1592x; 1.0742x over previous
//
#include <hip/hip_runtime.h>
#include <hip/hip_bf16.h>

// MyDeConv1D as GEMM: out[b,t,f] = sum_{j,c} x[b,t+28-4j,c]*W[c,j,f] + cnt(t)*256*bias[f]
// M=32768, N=256, K=2048, bf16 MFMA 16x16x32.
// R20 = R19 fixed: (1) raw asm s_barrier (opaque to LLVM convergence; counts
//   hand-matched 8/8 across roles), (2) B ring restored to R14 discipline
//   (2-ahead, 3 slots, VMW(8); slots consume/reserve/issue all distinct).
//   5 waves/block: 4 consumers (2m x 2f, 64x64; pure-B vmcnt queue) +
//   1 producer (all x HBM staging, 1 chunk ahead). 512 blocks = 2/CU.

#define B_   16
#define T_   2048
#define C_   256
#define KT   8
#define F_   256
#define SH   28
#define BT   128
#define ABFB 9984               // bytes per bf16 tile (156 rows x 64B)

typedef __attribute__((ext_vector_type(8))) short short8;
typedef __attribute__((ext_vector_type(4))) float floatx4;
typedef __attribute__((ext_vector_type(4))) int   intx4;

// Wf frag order: fid = S*16 + g, S = c*8 + j. frag (S,g): lane(l16,q) holds
// B[k=q*8+i][f=g*16+l16], c = c*32 + q*8 + i. 1KB/frag coalesced.
__global__ __launch_bounds__(256) void wprep_kernel(const float* __restrict__ W,
                                                    ushort* __restrict__ Wf) {
    const int tid  = threadIdx.x;
    const int fid  = blockIdx.x * 4 + (tid >> 6);   // 0..1023
    const int lane = tid & 63;
    const int g    = fid & 15;
    const int S    = fid >> 4;
    const int j    = S & 7, c = S >> 3;
    const int c0   = c * 32 + (lane >> 4) * 8;
    const int f    = g * 16 + (lane & 15);
    short8 pk;
    #pragma unroll
    for (int i = 0; i < 8; ++i) {
        __hip_bfloat16 h = __float2bfloat16(W[((c0 + i) * KT + j) * F_ + f]);
        pk[i] = *reinterpret_cast<const short*>(&h);
    }
    *reinterpret_cast<short8*>(Wf + (size_t)fid * 512 + lane * 8) = pk;
}

__device__ inline short8 cvt8v(floatx4 a, floatx4 b) {
    short8 r;
    #pragma unroll
    for (int i = 0; i < 4; ++i) {
        __hip_bfloat16 h = __float2bfloat16(a[i]);
        r[i] = *reinterpret_cast<const short*>(&h);
    }
    #pragma unroll
    for (int i = 0; i < 4; ++i) {
        __hip_bfloat16 h = __float2bfloat16(b[i]);
        r[i + 4] = *reinterpret_cast<const short*>(&h);
    }
    return r;
}

__global__ __launch_bounds__(320, 3) void deconv_kernel(
        const float* __restrict__ x, const ushort* __restrict__ Wf,
        const float* __restrict__ bias, float* __restrict__ out) {
    __shared__ alignas(16) char smem[2 * ABFB];     // 19968 B
    const int bid = blockIdx.x;                 // (tt*16 + b)*2 + fh
    const int fh  = bid & 1;
    const int tb  = bid >> 1;
    const int b   = tb & 15;
    const int t0  = (tb >> 4) * BT;
    const int tid = threadIdx.x;
    const int w   = tid >> 6, lane = tid & 63;
    const int l16 = lane & 15, q = lane >> 4;

#define VMW(N_) do { asm volatile("s_waitcnt vmcnt(" #N_ ")" ::: "memory"); \
        __builtin_amdgcn_sched_barrier(0); } while (0)
#define LKW() do { asm volatile("s_waitcnt lgkmcnt(0)" ::: "memory");       \
        __builtin_amdgcn_sched_barrier(0); } while (0)
#define BAR() do { __builtin_amdgcn_sched_barrier(0);                       \
        asm volatile("s_barrier" ::: "memory");                             \
        __builtin_amdgcn_sched_barrier(0); } while (0)

    if (w < 4) {
        // ================= CONSUMER: 4 waves, MFMA only =================
        const int wm = w >> 1, wf2 = w & 1;
        const char* wfbase = (const char*)Wf +
            (size_t)(fh * 8 + wf2 * 4) * 1024 + (size_t)lane * 16;

#define B_ISSUE(S_, sl_) do {                                               \
        const char* p_ = wfbase + (size_t)(S_) * 16384;                     \
        asm volatile("global_load_dwordx4 %0, %1, off"                      \
            : "=v"(bR[sl_][0]) : "v"(p_) : "memory");                       \
        asm volatile("global_load_dwordx4 %0, %1, off offset:1024"          \
            : "=v"(bR[sl_][1]) : "v"(p_) : "memory");                       \
        asm volatile("global_load_dwordx4 %0, %1, off offset:2048"          \
            : "=v"(bR[sl_][2]) : "v"(p_) : "memory");                       \
        asm volatile("global_load_dwordx4 %0, %1, off offset:3072"          \
            : "=v"(bR[sl_][3]) : "v"(p_) : "memory");                       \
        } while (0)

#define LOAD_A(buf_, j_, arr) do {                                          \
        const char* ab_ = smem + (buf_) * ABFB;                             \
        _Pragma("unroll")                                                   \
        for (int mf = 0; mf < 4; ++mf) {                                    \
            const int row_ = wm * 64 + (SH - 4 * (j_)) + mf * 16 + l16;     \
            const int p_   = q ^ ((row_ >> 1) & 3);                         \
            arr[mf] = *(const short8*)(ab_ + (row_ * 4 + p_) * 16);         \
        } } while (0)

#define MFMA_TAP(arr, slot_) do {                                           \
        __builtin_amdgcn_s_setprio(1);                                      \
        _Pragma("unroll")                                                   \
        for (int mf = 0; mf < 4; ++mf)                                      \
            _Pragma("unroll")                                               \
            for (int nf = 0; nf < 4; ++nf)                                  \
                acc[mf][nf] = __builtin_amdgcn_mfma_f32_16x16x32_bf16(      \
                    arr[mf], *(short8*)&bR[slot_][nf],                      \
                    acc[mf][nf], 0, 0, 0);                                  \
        __builtin_amdgcn_s_setprio(0);                                      \
        } while (0)

// tap: consume B(S) from slot S%3, issue B(S+2) into (S+2)%3 (distinct from
// S%3 and (S+1)%3), prefetch A(t+2).
#define CTAP(c_, t_, arr)                                                   \
        B_ISSUE((c_)*8+(t_)+2, (((c_)*8+(t_)+2)%3)); VMW(8);                \
        MFMA_TAP(arr, (((c_)*8+(t_))%3));                                   \
        if ((t_) < 6) LOAD_A((c_) & 1, (t_) + 2, arr);

#define CCHUNK(c_) do {                                                     \
        LOAD_A((c_) & 1, 0, a0); LOAD_A((c_) & 1, 1, a1);                   \
        CTAP(c_, 0, a0) CTAP(c_, 1, a1)                                     \
        CTAP(c_, 2, a0) CTAP(c_, 3, a1)                                     \
        CTAP(c_, 4, a0) CTAP(c_, 5, a1)                                     \
        CTAP(c_, 6, a0) CTAP(c_, 7, a1)                                     \
        BAR();                                                              \
        } while (0)

        float bf4[4];
        #pragma unroll
        for (int nf = 0; nf < 4; ++nf)
            bf4[nf] = bias[fh * 128 + wf2 * 64 + nf * 16 + l16];

        floatx4 acc[4][4];
        #pragma unroll
        for (int mf = 0; mf < 4; ++mf)
            #pragma unroll
            for (int nf = 0; nf < 4; ++nf)
                acc[mf][nf] = (floatx4){0.f, 0.f, 0.f, 0.f};

        short8 a0[4], a1[4];
        intx4  bR[3][4];

        // prologue: drain bias loads, prime B(0),B(1) -> 8 outstanding
        VMW(0);
        B_ISSUE(0, 0); B_ISSUE(1, 1);
        BAR();                                       // barrier #1

        CCHUNK(0); CCHUNK(1); CCHUNK(2); CCHUNK(3);  // barriers #2..#5
        CCHUNK(4); CCHUNK(5); CCHUNK(6);             // barriers #6..#8

        // chunk 7 (S = 56..63): entry outstanding = {B56,B57} = 8
        {
            LOAD_A(1, 0, a0); LOAD_A(1, 1, a1);
            B_ISSUE(58, 1); VMW(8); MFMA_TAP(a0, 2); LOAD_A(1, 2, a0);
            B_ISSUE(59, 2); VMW(8); MFMA_TAP(a1, 0); LOAD_A(1, 3, a1);
            B_ISSUE(60, 0); VMW(8); MFMA_TAP(a0, 1); LOAD_A(1, 4, a0);
            B_ISSUE(61, 1); VMW(8); MFMA_TAP(a1, 2); LOAD_A(1, 5, a1);
            B_ISSUE(62, 2); VMW(8); MFMA_TAP(a0, 0); LOAD_A(1, 6, a0);
            B_ISSUE(63, 0); VMW(8); MFMA_TAP(a1, 1); LOAD_A(1, 7, a1);
            VMW(4); MFMA_TAP(a0, 2);
            VMW(0); MFMA_TAP(a1, 0);
        }

        // epilogue: + cnt(t)*256*bias; C/D map col=l16 (f), row=q*4+r
        #pragma unroll
        for (int mf = 0; mf < 4; ++mf) {
            #pragma unroll
            for (int nf = 0; nf < 4; ++nf) {
                const int f = fh * 128 + wf2 * 64 + nf * 16 + l16;
                #pragma unroll
                for (int r = 0; r < 4; ++r) {
                    const int t = t0 + wm * 64 + mf * 16 + q * 4 + r;
                    const int jmin =
                        (t < T_ - SH) ? 0 : (((t - (T_ - SH)) >> 2) + 1);
                    out[(size_t)(b * T_ + t) * F_ + f] =
                        acc[mf][nf][r] + (float)(8 - jmin) * 256.0f * bf4[nf];
                }
            }
        }
#undef B_ISSUE
#undef LOAD_A
#undef MFMA_TAP
#undef CTAP
#undef CCHUNK
    } else {
        // ================= PRODUCER: 1 wave, all x staging =================
        floatx4 ps[10][2];

#define PROD_LOAD(r_, cs_) do {                                             \
        const int u_ = (r_) * 64 + lane;                                    \
        const int row_ = u_ >> 2, pp_ = u_ & 3;                             \
        const int g_ = pp_ ^ ((row_ >> 1) & 3);                             \
        int tr_ = t0 + row_; if (tr_ > T_ - 1) tr_ = T_ - 1;                \
        const char* p_ = (const char*)(x +                                  \
            ((size_t)(b * T_ + tr_) * C_ + (cs_) * 32 + g_ * 8));           \
        asm volatile("global_load_dwordx4 %0, %1, off"                      \
            : "=v"(ps[r_][0]) : "v"(p_) : "memory");                        \
        asm volatile("global_load_dwordx4 %0, %1, off offset:16"            \
            : "=v"(ps[r_][1]) : "v"(p_) : "memory");                        \
        } while (0)

#define PROD_WRITE(r_, buf_) do {                                           \
        const int u_ = (r_) * 64 + lane;                                    \
        const int row_ = u_ >> 2, pp_ = u_ & 3;                             \
        if ((r_) < 9 || row_ < 156) {                                       \
            short8 pk_ = {0,0,0,0,0,0,0,0};                                 \
            if (t0 + row_ < T_) pk_ = cvt8v(ps[r_][0], ps[r_][1]);          \
            *(short8*)(smem + (buf_) * ABFB + (row_ * 4 + pp_) * 16) = pk_; \
        } } while (0)

#define PROD_STAGE(cs_, buf_) do {                                          \
        PROD_LOAD(0, cs_); PROD_LOAD(1, cs_); PROD_LOAD(2, cs_);            \
        PROD_LOAD(3, cs_); PROD_LOAD(4, cs_); PROD_LOAD(5, cs_);            \
        PROD_LOAD(6, cs_); PROD_LOAD(7, cs_); PROD_LOAD(8, cs_);            \
        PROD_LOAD(9, cs_);                                                  \
        VMW(0);                                                             \
        PROD_WRITE(0, buf_); PROD_WRITE(1, buf_); PROD_WRITE(2, buf_);      \
        PROD_WRITE(3, buf_); PROD_WRITE(4, buf_); PROD_WRITE(5, buf_);      \
        PROD_WRITE(6, buf_); PROD_WRITE(7, buf_); PROD_WRITE(8, buf_);      \
        PROD_WRITE(9, buf_);                                                \
        LKW();                                                              \
        } while (0)

        PROD_STAGE(0, 0);
        BAR();                          // barrier #1: tile 0 ready
        PROD_STAGE(1, 1); BAR();        // #2
        PROD_STAGE(2, 0); BAR();        // #3
        PROD_STAGE(3, 1); BAR();        // #4
        PROD_STAGE(4, 0); BAR();        // #5
        PROD_STAGE(5, 1); BAR();        // #6
        PROD_STAGE(6, 0); BAR();        // #7
        PROD_STAGE(7, 1); BAR();        // #8
#undef PROD_LOAD
#undef PROD_WRITE
#undef PROD_STAGE
    }
#undef VMW
#undef LKW
#undef BAR
}

extern "C" void kernel_launch(void* const* d_in, const int* in_sizes, int n_in,
                              void* d_out, int out_size, void* d_ws, size_t ws_size,
                              hipStream_t stream) {
    const float* x    = (const float*)d_in[0];
    const float* W    = (const float*)d_in[1];   // (C,KT,F)
    const float* bias = (const float*)d_in[2];
    float* out = (float*)d_out;
    ushort* Wf = (ushort*)d_ws;                  // 1 MiB scratch

    wprep_kernel<<<256, 256, 0, stream>>>(W, Wf);
    deconv_kernel<<<512, 320, 0, stream>>>(x, Wf, bias, out);
}